// Round 10
// baseline (297.863 us; speedup 1.0000x reference)
//
#include <hip/hip_runtime.h>

typedef _Float16 half8 __attribute__((ext_vector_type(8)));
typedef _Float16 half4v __attribute__((ext_vector_type(4)));
typedef float f32x4 __attribute__((ext_vector_type(4)));

// async global->LDS, 16 B per lane; LDS dest is wave-uniform base + lane*16
#define GLD16(gptr, lptr) \
    __builtin_amdgcn_global_load_lds((const __attribute__((address_space(1))) void*)(gptr), \
                                     (__attribute__((address_space(3))) void*)(lptr), 16, 0, 0)

// s_waitcnt immediates: vmcnt [3:0]|[15:14], expcnt [6:4], lgkmcnt [11:8]
#define WAIT_VM3   0x0F73  // vmcnt(3)
#define WAIT_VM0   0x0F70  // vmcnt(0)
#define WAIT_LGKM0 0xC07F  // lgkmcnt(0)

// ---------------------------------------------------------------------------
// GEMM descriptor (two independent GEMMs share one launch via blockIdx.z).
// zz = bz / SK; s = bz % SK; h = ahx ? bx : zz & hmask; g = ahx ? zz : zz>>hshift.
// A += h*sAh + g*sAg; B += h*sBh + g*sBg; Coff = s*sSplit + h*sCh + g*sCg.
// normMode: 0 plain; 1 q-norm; 2 kv-norm (+vn; raw V -> xcat right half).
// atomOut: plain path does unsafeAtomicAdd f32 into C (bias pre-seeded by
// prep) — replaces the split-K partial buffers + finalize dispatch.
// ---------------------------------------------------------------------------
struct GD {
    const _Float16* A; const _Float16* B; void* C;
    const float* colScale;
    _Float16 *vnp, *vtp, *xop;
    long sAh, sAg, sBh, sBg, sSplit, sCh, sCg;
    int lda, ldb, ldc, K, SK, hmask, hshift;
    int ahx, outHalf, csMode, nx, ny, normMode, atomOut;
    float alpha;
};

// ---------------------------------------------------------------------------
// hgemm3 (round-7 proven form, best measured: M1 = 40.8 µs): 256x128 tile,
// BK=32, 512 threads (8 waves of 64x64, 4M x 2N), 3-slot LDS ring (72 KB ->
// 2 blocks/CU), depth-2 prefetch, ONE barrier per K-step, counted vmcnt.
// Frozen: 128^2 tile regressed (r8), phase-split/setprio regressed (r6),
// XCD swizzle null (r5), deep ring null (r1), occupancy bump null (r3).
//
// Staging: LDS row-major [row][32 halves]; each GLD16 = 16 rows x 64 B,
// 4 lanes per aligned line (coalesced). Bank-conflict fix (both-sides):
// LDS 16-B slot s of row r holds global chunk c = s ^ ((r>>1)&3); frag reads
// use slot = kq ^ ((lm>>1)&3)  (SQ_LDS_BANK_CONFLICT == 0 measured).
// Ring safety: stage(t+2) targets slot (t-1)%3 whose readers retired
// (lgkmcnt(0)) before the barrier that opened step t.
// ---------------------------------------------------------------------------
__global__ __launch_bounds__(512, 4)
void hgemm3(GD d0, GD d1, int zSplit)
{
    const bool second = (int)blockIdx.z >= zSplit;
    const GD& d = second ? d1 : d0;
    const int bz = second ? (int)blockIdx.z - zSplit : (int)blockIdx.z;
    const int bx = (int)blockIdx.x, by = (int)blockIdx.y;
    if (bx >= d.nx || by >= d.ny) return;

    __shared__ uint4 smem[4608];          // 72 KB: 3 ring slots x 24 KB
    char* sb = (char*)smem;
    const int tid = threadIdx.x;
    const int w = tid >> 6, l = tid & 63;
    const int m0 = by << 8, n0 = bx << 7;
    const int wm = (w >> 1) << 6, wn = (w & 1) << 6;
    const int kq = l >> 4, lm = l & 15;

    const int zz = bz / d.SK, s = bz - zz * d.SK;
    const int h = d.ahx ? bx : (zz & d.hmask);
    const int g = d.ahx ? zz : (zz >> d.hshift);
    const _Float16* A = d.A + (long)h * d.sAh + (long)g * d.sAg;
    const _Float16* B = d.B + (long)h * d.sBh + (long)g * d.sBg;
    const long Coff = (long)s * d.sSplit + (long)h * d.sCh + (long)g * d.sCg;
    const int kper = d.K / d.SK, kbeg = s * kper;
    const int NT = kper >> 5;

    // staging: each instr = 16 rows x 64 B, 4 lanes per full line.
    const int rS = (w << 4) + (l >> 2);
    const int cS = (l & 3) ^ ((l >> 3) & 3);      // slot ^ ((rS>>1)&3)
    const _Float16* gA0 = A + (long)(m0 + rS) * d.lda + kbeg + cS * 8;
    const _Float16* gB0 = B + (long)(n0 + rS) * d.ldb + kbeg + cS * 8;
    const int lo = w * 1024 + l * 16;

    auto stage = [&](int t) {
        char* dst = sb + (t % 3) * 24576;
        GLD16(gA0 + t * 32,                     dst + lo);           // A rows 0-127
        GLD16(gA0 + (long)128 * d.lda + t * 32, dst + 8192 + lo);    // A rows 128-255
        GLD16(gB0 + t * 32,                     dst + 16384 + lo);   // B rows 0-127
    };

    f32x4 acc[4][4] = {};
    stage(0);
    if (NT > 1) stage(1);
    if (NT > 1) __builtin_amdgcn_s_waitcnt(WAIT_VM3);
    else        __builtin_amdgcn_s_waitcnt(WAIT_VM0);
    __builtin_amdgcn_s_barrier();

    const int sw16 = ((kq ^ ((lm >> 1) & 3)) << 4);   // swizzled 16-B slot
    for (int t = 0; t < NT; ++t) {
        const char* cb = sb + (t % 3) * 24576;
        half8 af[4], bfr[4];
        const char* pa = cb + (wm + lm) * 64 + sw16;
        const char* pb = cb + 16384 + (wn + lm) * 64 + sw16;
        #pragma unroll
        for (int i = 0; i < 4; ++i) {
            af[i]  = *(const half8*)(pa + i * 1024);
            bfr[i] = *(const half8*)(pb + i * 1024);
        }
        #pragma unroll
        for (int mi = 0; mi < 4; ++mi)
            #pragma unroll
            for (int ni = 0; ni < 4; ++ni)
                acc[mi][ni] = __builtin_amdgcn_mfma_f32_16x16x32_f16(af[mi], bfr[ni], acc[mi][ni], 0, 0, 0);
        __builtin_amdgcn_s_waitcnt(WAIT_LGKM0);       // our ds_reads retired
        if (t + 2 < NT) { stage(t + 2); __builtin_amdgcn_s_waitcnt(WAIT_VM3); }
        else if (t + 1 < NT) __builtin_amdgcn_s_waitcnt(WAIT_VM0);
        __builtin_amdgcn_s_barrier();                 // tile t+1 landed+visible
    }

    // C/D layout: col = lane&15, row = (lane>>4)*4 + reg
    if (d.normMode == 0) {
        const int rbase = m0 + wm + kq * 4;
        #pragma unroll
        for (int mi = 0; mi < 4; ++mi) {
            #pragma unroll
            for (int ni = 0; ni < 4; ++ni) {
                const int col = n0 + wn + ni * 16 + lm;
                float cs = d.alpha;
                if (d.csMode == 1 || (d.csMode == 2 && g == 0)) cs *= d.colScale[col];
                #pragma unroll
                for (int r = 0; r < 4; ++r) {
                    const long row = rbase + mi * 16 + r;
                    const float v = acc[mi][ni][r] * cs;
                    const long off = Coff + row * d.ldc + col;
                    if (d.atomOut)      unsafeAtomicAdd((float*)d.C + off, v);
                    else if (d.outHalf) ((_Float16*)d.C)[off] = (_Float16)v;
                    else                ((float*)d.C)[off] = v;
                }
            }
        }
        return;
    }

    // ---- fused L2-norm epilogue (block cols = exactly one 128-dim head) ----
    float* part = (float*)sb;                 // part[2][256]
    float ssq[4][4];
    #pragma unroll
    for (int mi = 0; mi < 4; ++mi)
        #pragma unroll
        for (int r = 0; r < 4; ++r) {
            float sq = 0.f;
            #pragma unroll
            for (int ni = 0; ni < 4; ++ni) { const float v = acc[mi][ni][r]; sq += v * v; }
            sq += __shfl_xor(sq, 1, 64);
            sq += __shfl_xor(sq, 2, 64);
            sq += __shfl_xor(sq, 4, 64);
            sq += __shfl_xor(sq, 8, 64);
            ssq[mi][r] = sq;
        }
    if (lm == 0) {
        #pragma unroll
        for (int mi = 0; mi < 4; ++mi)
            #pragma unroll
            for (int r = 0; r < 4; ++r)
                part[(w & 1) * 256 + wm + kq * 4 + mi * 16 + r] = ssq[mi][r];
    }
    __syncthreads();

    #pragma unroll
    for (int mi = 0; mi < 4; ++mi) {
        #pragma unroll
        for (int r = 0; r < 4; ++r) {
            const int rl = wm + kq * 4 + mi * 16 + r;
            const float inv = rsqrtf(part[rl] + part[256 + rl]);
            const long rg = m0 + rl;
            if (d.normMode == 1) {
                #pragma unroll
                for (int ni = 0; ni < 4; ++ni) {
                    const int col = n0 + wn + ni * 16 + lm;
                    ((_Float16*)d.C)[(long)g * 524288 + rg * 1024 + col] =
                        (_Float16)(acc[mi][ni][r] * inv);
                }
            } else if (n0 < 1024) {           // K half -> kn
                #pragma unroll
                for (int ni = 0; ni < 4; ++ni) {
                    const int col = n0 + wn + ni * 16 + lm;
                    ((_Float16*)d.C)[(long)g * 2097152 + rg * 1024 + col] =
                        (_Float16)(acc[mi][ni][r] * inv);
                }
            } else {                          // V half -> vn + xcat right half
                #pragma unroll
                for (int ni = 0; ni < 4; ++ni) {
                    const int nL = n0 - 1024 + wn + ni * 16 + lm;
                    d.vnp[(long)g * 2097152 + rg * 1024 + nL] =
                        (_Float16)(acc[mi][ni][r] * inv);
                    if (rg < 512)
                        d.xop[((long)g * 512 + rg) * 2048 + 1024 + nL] =
                            (_Float16)acc[mi][ni][r];
                }
            }
        }
    }
    // vT raw transposed store (V half)
    if (d.normMode == 2 && n0 >= 1024) {
        #pragma unroll
        for (int mi = 0; mi < 4; ++mi)
            #pragma unroll
            for (int ni = 0; ni < 4; ++ni) {
                const int nL = n0 - 1024 + wn + ni * 16 + lm;
                half4v t;
                t.x = (_Float16)acc[mi][ni][0]; t.y = (_Float16)acc[mi][ni][1];
                t.z = (_Float16)acc[mi][ni][2]; t.w = (_Float16)acc[mi][ni][3];
                *(half4v*)(d.vtp + (long)g * 2097152 + (long)nL * 2048
                           + m0 + wm + kq * 4 + mi * 16) = t;
            }
    }
}

static GD mkgd(const _Float16* A, const _Float16* B, void* C, const float* cscale,
               long sAh, long sAg, long sBh, long sBg, long sSplit, long sCh, long sCg,
               int lda, int ldb, int ldc, int K, int SK, int hmask, int hshift,
               int ahx, int outHalf, int csMode, int nx, int ny, float alpha)
{
    GD d; d.A=A; d.B=B; d.C=C; d.colScale=cscale;
    d.vnp=nullptr; d.vtp=nullptr; d.xop=nullptr;
    d.sAh=sAh; d.sAg=sAg; d.sBh=sBh; d.sBg=sBg; d.sSplit=sSplit; d.sCh=sCh; d.sCg=sCg;
    d.lda=lda; d.ldb=ldb; d.ldc=ldc; d.K=K; d.SK=SK; d.hmask=hmask; d.hshift=hshift;
    d.ahx=ahx; d.outHalf=outHalf; d.csMode=csMode; d.nx=nx; d.ny=ny; d.normMode=0;
    d.atomOut=0; d.alpha=alpha;
    return d;
}

// ---------------------------------------------------------------------------
// prep_all: grid (64,64,8). z<6: weight transposes (f32 -> f16 T);
// z==6: fp32->fp16 cast of x_cls|x_reg; z==7: seed d_out with bias (cols>=
// 1024) / zeros (cols<1024) so M3-ae / M8-ol can atomicAdd into it.
// ---------------------------------------------------------------------------
__global__ __launch_bounds__(256)
void prep_all(const float* __restrict__ x_cls, const float* __restrict__ x_reg,
              const float* __restrict__ Wq_c, const float* __restrict__ Wq_r,
              const float* __restrict__ Wkv_c, const float* __restrict__ Wkv_r,
              const float* __restrict__ Wl_c, const float* __restrict__ Wl_r,
              const float* __restrict__ b_lin, const float* __restrict__ b_lin_reg,
              _Float16* __restrict__ xbf,
              _Float16* __restrict__ WqT, _Float16* __restrict__ WkvT,
              _Float16* __restrict__ WlinT, float* __restrict__ out)
{
    const int z = blockIdx.z;
    if (z == 6) {
        const int lin = blockIdx.y * 64 + blockIdx.x;    // [0,4096)
        const int which = lin >> 11;
        const int i = (lin & 2047) * 256 + threadIdx.x;  // float4 index
        const float* s = which ? x_reg : x_cls;
        const float4 v = ((const float4*)s)[i];
        half4v o;
        o.x = (_Float16)v.x; o.y = (_Float16)v.y; o.z = (_Float16)v.z; o.w = (_Float16)v.w;
        ((half4v*)(xbf + (size_t)which * 2097152))[i] = o;
        return;
    }
    if (z == 7) {
        const int lin = blockIdx.y * 64 + blockIdx.x;    // need [0,3072)
        if (lin >= 3072) return;
        const size_t base = ((size_t)lin * 256 + threadIdx.x) * 4;  // < 3145728
        const int c = (int)(base % 3072);
        const int g = (int)(base / (3072 * 512));
        float4 v;
        if (c < 1024) v = make_float4(0.f, 0.f, 0.f, 0.f);
        else          v = *(const float4*)((g ? b_lin_reg : b_lin) + (c - 1024));
        *(float4*)(out + base) = v;
        return;
    }
    __shared__ float t[32][33];
    const float* src; _Float16* dst; int ldsrc, lddst, nx, ky;
    switch (z) {
        case 0: src=Wq_c;  dst=WqT;            ldsrc=1024; lddst=1024; nx=32; ky=32; break;
        case 1: src=Wq_r;  dst=WqT+1048576;    ldsrc=1024; lddst=1024; nx=32; ky=32; break;
        case 2: src=Wkv_c; dst=WkvT;           ldsrc=2048; lddst=1024; nx=64; ky=32; break;
        case 3: src=Wkv_r; dst=WkvT+2097152;   ldsrc=2048; lddst=1024; nx=64; ky=32; break;
        case 4: src=Wl_c;  dst=WlinT;          ldsrc=2048; lddst=2048; nx=64; ky=64; break;
        default:src=Wl_r;  dst=WlinT+4194304;  ldsrc=2048; lddst=2048; nx=64; ky=64; break;
    }
    if ((int)blockIdx.x >= nx || (int)blockIdx.y >= ky) return;
    const int n0 = blockIdx.x << 5, k0 = blockIdx.y << 5;
    const int tx = threadIdx.x & 31, ty = threadIdx.x >> 5;
    #pragma unroll
    for (int j = ty; j < 32; j += 8)
        t[j][tx] = src[(size_t)(k0 + j) * ldsrc + n0 + tx];
    __syncthreads();
    #pragma unroll
    for (int j = ty; j < 32; j += 8)
        dst[(size_t)(n0 + j) * lddst + k0 + tx] = (_Float16)t[tx][j];
}

// ---------------------------------------------------------------------------
// Paired block reduce (256 threads, 4 waves). OP: 0 sum, 1 max.
// ---------------------------------------------------------------------------
template<int OP>
__device__ __forceinline__ void bred2(float& a, float& b, float* lds)
{
    #pragma unroll
    for (int o = 32; o > 0; o >>= 1) {
        const float ua = __shfl_xor(a, o, 64);
        const float ub = __shfl_xor(b, o, 64);
        a = OP ? fmaxf(a, ua) : a + ua;
        b = OP ? fmaxf(b, ub) : b + ub;
    }
    __syncthreads();
    if ((threadIdx.x & 63) == 0) {
        const int wi = threadIdx.x >> 6;
        lds[wi] = a; lds[4 + wi] = b;
    }
    __syncthreads();
    a = OP ? fmaxf(fmaxf(lds[0], lds[1]), fmaxf(lds[2], lds[3]))
           : lds[0] + lds[1] + lds[2] + lds[3];
    b = OP ? fmaxf(fmaxf(lds[4], lds[5]), fmaxf(lds[6], lds[7]))
           : lds[4] + lds[5] + lds[6] + lds[7];
}

// ---------------------------------------------------------------------------
// sb2 (vectorized; NO max-subtraction): scores are bounded (|cos|<=1 ->
// |S| <= 25.1, exp <= 8e10 << f32 max; head-mean <= 1 -> exp <= e), so
// exp(x)/sum exp(x) is safe in f32 and mathematically identical to the
// max-subtracted softmax. Barriers: 18 vs 38.
// Thread t owns 8 contiguous cols. S16 [16][512][2048] fp16 (0-7 cls,
// 8-15 reg); simPart [2s][2g][512][2048] f32 (2-way split-K summed here).
// ---------------------------------------------------------------------------
__global__ __launch_bounds__(256)
void sb2_kernel(const _Float16* __restrict__ S16, const float* __restrict__ simPart,
                _Float16* __restrict__ attn,
                _Float16* __restrict__ wc, _Float16* __restrict__ wr)
{
    __shared__ float lds[8];
    const int q = blockIdx.x, t = threadIdx.x;
    const int c0 = t * 8;
    float asum[8] = {};
    for (int hh = 0; hh < 8; ++hh) {
        const size_t rb = (size_t)(hh * 512 + q) * 2048 + c0;
        const half8 hc = *(const half8*)(S16 + rb);
        const half8 hr = *(const half8*)(S16 + 8388608 + rb);
        float vc[8], vr[8];
        float sc = 0.f, sr = 0.f;
        #pragma unroll
        for (int j = 0; j < 8; ++j) {
            vc[j] = expf((float)hc[j]); sc += vc[j];
            vr[j] = expf((float)hr[j]); sr += vr[j];
        }
        bred2<0>(sc, sr, lds);
        const float ic = 0.5f / sc, ir = 0.5f / sr;
        half8 oa;
        #pragma unroll
        for (int j = 0; j < 8; ++j) {
            const float a = vc[j] * ic + vr[j] * ir;
            oa[j] = (_Float16)a;
            asum[j] += a;
        }
        *(half8*)(attn + rb) = oa;
    }
    const size_t qb = (size_t)q * 2048 + c0;
    float sim[8], reg[8];
    {
        const float4 a0 = *(const float4*)(simPart + qb);
        const float4 a1 = *(const float4*)(simPart + qb + 4);
        const float4 b0 = *(const float4*)(simPart + 2097152 + qb);
        const float4 b1 = *(const float4*)(simPart + 2097152 + qb + 4);
        sim[0]=a0.x+b0.x; sim[1]=a0.y+b0.y; sim[2]=a0.z+b0.z; sim[3]=a0.w+b0.w;
        sim[4]=a1.x+b1.x; sim[5]=a1.y+b1.y; sim[6]=a1.z+b1.z; sim[7]=a1.w+b1.w;
        const float4 c0_ = *(const float4*)(simPart + 1048576 + qb);
        const float4 c1_ = *(const float4*)(simPart + 1048576 + qb + 4);
        const float4 d0_ = *(const float4*)(simPart + 2097152 + 1048576 + qb);
        const float4 d1_ = *(const float4*)(simPart + 2097152 + 1048576 + qb + 4);
        reg[0]=c0_.x+d0_.x; reg[1]=c0_.y+d0_.y; reg[2]=c0_.z+d0_.z; reg[3]=c0_.w+d0_.w;
        reg[4]=c1_.x+d1_.x; reg[5]=c1_.y+d1_.y; reg[6]=c1_.z+d1_.z; reg[7]=c1_.w+d1_.w;
    }
    float em[8], emo[8];
    float s1 = 0.f, s2 = 0.f;
    #pragma unroll
    for (int j = 0; j < 8; ++j) {
        const float e = expf(asum[j] * 0.125f);       // bounded by e^1
        const float m  = sim[j] > 0.75f ? 1.f : 0.f;
        const float mo = reg[j] > 0.99f ? 1.f : 0.f;
        em[j] = e * m; emo[j] = e * m * mo;
        s1 += em[j]; s2 += emo[j];
    }
    bred2<0>(s1, s2, lds);
    const float i1 = 1.f / s1, i2 = 1.f / s2;
    half8 o1, o2;
    #pragma unroll
    for (int j = 0; j < 8; ++j) {
        o1[j] = (_Float16)(em[j] * i1);
        o2[j] = (_Float16)(emo[j] * i2);
    }
    *(half8*)(wc + qb) = o1;
    *(half8*)(wr + qb) = o2;
}

// ---------------------------------------------------------------------------
// build_xcat (left half only; right half written by M1 epilogue):
// xcat[g][n][j<1024] = 4-way reduce of fp16 attn@V partials. Grid 512 x 256,
// half8-vectorized.
// ---------------------------------------------------------------------------
__global__ __launch_bounds__(256)
void build_xcat(const _Float16* __restrict__ xcatPart, _Float16* __restrict__ xcat)
{
    const int v8 = blockIdx.x * 256 + threadIdx.x;    // [0, 131072)
    const int g = v8 >> 16;
    const int n = (v8 >> 7) & 511;
    const int j = (v8 & 127) * 8;
    const size_t p = (size_t)g * 524288 + (size_t)n * 1024 + j;
    float a[8] = {};
    #pragma unroll
    for (int s = 0; s < 4; ++s) {
        const half8 v = *(const half8*)(xcatPart + (size_t)s * 1048576 + p);
        #pragma unroll
        for (int k = 0; k < 8; ++k) a[k] += (float)v[k];
    }
    half8 o;
    #pragma unroll
    for (int k = 0; k < 8; ++k) o[k] = (_Float16)a[k];
    *(half8*)(xcat + ((size_t)g * 512 + n) * 2048 + j) = o;
}

extern "C" void kernel_launch(void* const* d_in, const int* in_sizes, int n_in,
                              void* d_out, int out_size, void* d_ws, size_t ws_size,
                              hipStream_t stream)
{
    const float* x_cls     = (const float*)d_in[0];
    const float* x_reg     = (const float*)d_in[1];
    const float* cls_score = (const float*)d_in[2];
    const float* W_q_cls   = (const float*)d_in[4];
    const float* W_kv_cls  = (const float*)d_in[5];
    const float* W_q_reg   = (const float*)d_in[6];
    const float* W_kv_reg  = (const float*)d_in[7];
    const float* W_lin     = (const float*)d_in[8];
    const float* b_lin     = (const float*)d_in[9];
    const float* W_lin_reg = (const float*)d_in[10];
    const float* b_lin_reg = (const float*)d_in[11];
    float* out = (float*)d_out;

    if (ws_size < (size_t)124 * 1048576) return;

    // Workspace overlay (MiB offsets), peak 106 MiB. Lifetimes:
    //  [0,16)   WlinT    prep -> M8
    //  [16,24)  vT       M1 -> M3
    //  [24,26)  w_c      sb2 -> M3        [26,28) w_r
    //  [28,30)  qn       M1 -> M2(sc)   } attn_h [28,44) overlays after M2
    //  [30,38)  kn       M1 -> M2(sc)   }
    //  [38,46)  vn       M1 -> M2(vs)   }
    //  [46,54)  xbf      prep -> M1     } simPart [46,62) overlays after M1
    //  [54,62)  WkvT     prep -> M1     }
    //  [62,66)  WqT      prep -> M1     } xcatPart [62,70) overlays after sb2
    //  [66,98)  S16      M2(sc) -> sb2  }  (S16 dead after sb2)
    //  [102,106) xcat16  M1(right)+build_xcat(left) -> M8
    char* W = (char*)d_ws;
    auto at = [&](size_t mb) { return (void*)(W + mb * 1048576); };
    _Float16* WlinT   = (_Float16*)at(0);
    _Float16* vT      = (_Float16*)at(16);
    _Float16* w_c     = (_Float16*)at(24);
    _Float16* w_r     = (_Float16*)at(26);
    _Float16* qn      = (_Float16*)at(28);
    _Float16* kn      = (_Float16*)at(30);
    _Float16* vn      = (_Float16*)at(38);
    _Float16* xbf     = (_Float16*)at(46);
    _Float16* WkvT    = (_Float16*)at(54);
    _Float16* WqT     = (_Float16*)at(62);
    _Float16* S16     = (_Float16*)at(66);
    float*    simPart = (float*)at(46);      // [2s][2g][512][2048] f32, 16 MB
    _Float16* attn_h  = (_Float16*)at(28);   // [8][512][2048] fp16, 16 MB
    _Float16* xcatPart= (_Float16*)at(62);   // [4s][2g][512][1024] fp16, 8 MB
    _Float16* xcat16  = (_Float16*)at(102);  // [2][512][2048] fp16, 4 MB

    // Phase 1: prep (cast + transposes + out bias-seed, one launch)
    prep_all<<<dim3(64, 64, 8), 256, 0, stream>>>(
        x_cls, x_reg, W_q_cls, W_q_reg, W_kv_cls, W_kv_reg, W_lin, W_lin_reg,
        b_lin, b_lin_reg, xbf, WqT, WkvT, WlinT, out);

    // Phase 2 (M1): q-proj + kv-proj with fused L2-norm epilogues; kv also
    // writes raw V (rows<512) straight into xcat16's right half.
    {
        GD q  = mkgd(xbf, WqT, qn, nullptr,
                     0, 2097152, 0, 1048576, 0, 0, 0,
                     1024, 1024, 1024, 1024, 1, 0, 0, 1, 0, 0, 8, 2, 1.f);
        q.normMode = 1;
        GD kv = mkgd(xbf, WkvT, kn, nullptr,
                     0, 2097152, 0, 2097152, 0, 0, 0,
                     1024, 1024, 1024, 1024, 1, 0, 0, 1, 0, 0, 16, 8, 1.f);
        kv.normMode = 2; kv.vnp = vn; kv.vtp = vT; kv.xop = xcat16;
        hgemm3<<<dim3(16, 8, 4), 512, 0, stream>>>(q, kv, 2);
    }

    // Phase 3 (M2): v-sim (SK=2, f32 partials -> summed in sb2) + scores
    {
        GD vs = mkgd(vn, vn, simPart, nullptr,
                     0, 2097152, 0, 2097152, 2097152, 0, 1048576,
                     1024, 1024, 2048, 1024, 2, 0, 0, 0, 0, 0, 16, 2, 0.125f);
        GD sc = mkgd(qn, kn, S16, cls_score,
                     128, 524288, 128, 2097152, 0, 1048576, 8388608,
                     1024, 1024, 2048, 128, 1, 7, 3, 0, 1, 2, 16, 2, 25.f);
        hgemm3<<<dim3(16, 2, 20), 512, 0, stream>>>(vs, sc, 4);
    }

    // Phase 4: fused dual softmax + blend + head-mean + round2 weights
    sb2_kernel<<<512, 256, 0, stream>>>(S16, simPart, attn_h, w_c, w_r);

    // Phase 5 (M3): attn@V (AHX, SK=4, fp16 partials) + ave (SK=4,
    // atomicAdd f32 into bias-seeded out cols<1024 — finalize eliminated)
    {
        GD av = mkgd(attn_h, vT, xcatPart, nullptr,
                     1048576, 0, 0, 2097152, 1048576, 0, 524288,
                     2048, 2048, 1024, 2048, 4, 0, 0, 1, 1, 0, 8, 2, 1.f);
        GD ae = mkgd(w_c, vT, out, nullptr,
                     0, 1048576, 0, 2097152, 0, 0, 1572864,
                     2048, 2048, 3072, 2048, 4, 0, 0, 0, 0, 0, 8, 2, 1.f);
        ae.atomOut = 1;
        hgemm3<<<dim3(8, 2, 16), 512, 0, stream>>>(av, ae, 8);
    }

    // Phase 6: xcat left-half assembly (4-way fp16 reduce), half8-vectorized
    build_xcat<<<512, 256, 0, stream>>>(xcatPart, xcat16);

    // Phase 7 (M8): out-linears (SK=4, atomicAdd f32 into out cols>=1024)
    {
        GD ol = mkgd(xcat16, WlinT, out + 1024, nullptr,
                     0, 1048576, 0, 4194304, 0, 0, 1572864,
                     2048, 2048, 3072, 2048, 4, 0, 0, 0, 0, 0, 16, 2, 1.f);
        ol.atomOut = 1;
        hgemm3<<<dim3(16, 2, 8), 512, 0, stream>>>(ol, ol, 8);
    }
}

// Round 11
// 266.737 us; speedup vs baseline: 1.1167x; 1.1167x over previous
//
#include <hip/hip_runtime.h>

typedef _Float16 half8 __attribute__((ext_vector_type(8)));
typedef _Float16 half4v __attribute__((ext_vector_type(4)));
typedef float f32x4 __attribute__((ext_vector_type(4)));

// async global->LDS, 16 B per lane; LDS dest is wave-uniform base + lane*16
#define GLD16(gptr, lptr) \
    __builtin_amdgcn_global_load_lds((const __attribute__((address_space(1))) void*)(gptr), \
                                     (__attribute__((address_space(3))) void*)(lptr), 16, 0, 0)

// s_waitcnt immediates: vmcnt [3:0]|[15:14], expcnt [6:4], lgkmcnt [11:8]
#define WAIT_VM3   0x0F73  // vmcnt(3)
#define WAIT_VM0   0x0F70  // vmcnt(0)
#define WAIT_LGKM0 0xC07F  // lgkmcnt(0)

// ---------------------------------------------------------------------------
// GEMM descriptor (two independent GEMMs share one launch via blockIdx.z).
// zz = bz / SK; s = bz % SK; h = ahx ? bx : zz & hmask; g = ahx ? zz : zz>>hshift.
// A += h*sAh + g*sAg; B += h*sBh + g*sBg; Coff = s*sSplit + h*sCh + g*sCg.
// normMode: 0 plain; 1 q-norm; 2 kv-norm (+vn; raw V -> xcat right half).
// ---------------------------------------------------------------------------
struct GD {
    const _Float16* A; const _Float16* B; void* C;
    const float* colScale;
    _Float16 *vnp, *vtp, *xop;
    long sAh, sAg, sBh, sBg, sSplit, sCh, sCg;
    int lda, ldb, ldc, K, SK, hmask, hshift;
    int ahx, outHalf, csMode, nx, ny, normMode;   // csMode: 0 none, 1 always, 2 g==0
    float alpha;
};

// ---------------------------------------------------------------------------
// hgemm3 (round-7/9 proven form, best measured: M1 = 40.8 µs): 256x128 tile,
// BK=32, 512 threads (8 waves of 64x64, 4M x 2N), 3-slot LDS ring (72 KB ->
// 2 blocks/CU), depth-2 prefetch, ONE barrier per K-step, counted vmcnt.
// Frozen-out by measurement: 128^2 tile (r8, −14%), phase-split/setprio
// (r6, −12%), XCD swizzle (r5, null), deep ring (r1, null), occupancy bump
// (r3, null), atomicAdd epilogue (r10, −10% total: 4-way same-line atomic
// contention + lost store-combining).
//
// Staging: LDS row-major [row][32 halves]; each GLD16 = 16 rows x 64 B,
// 4 lanes per aligned line (coalesced). Bank-conflict fix (both-sides):
// LDS 16-B slot s of row r holds global chunk c = s ^ ((r>>1)&3); frag reads
// use slot = kq ^ ((lm>>1)&3)  (SQ_LDS_BANK_CONFLICT == 0 measured).
// Ring safety: stage(t+2) targets slot (t-1)%3 whose readers retired
// (lgkmcnt(0)) before the barrier that opened step t.
// ---------------------------------------------------------------------------
__global__ __launch_bounds__(512, 4)
void hgemm3(GD d0, GD d1, int zSplit)
{
    const bool second = (int)blockIdx.z >= zSplit;
    const GD& d = second ? d1 : d0;
    const int bz = second ? (int)blockIdx.z - zSplit : (int)blockIdx.z;
    const int bx = (int)blockIdx.x, by = (int)blockIdx.y;
    if (bx >= d.nx || by >= d.ny) return;

    __shared__ uint4 smem[4608];          // 72 KB: 3 ring slots x 24 KB
    char* sb = (char*)smem;
    const int tid = threadIdx.x;
    const int w = tid >> 6, l = tid & 63;
    const int m0 = by << 8, n0 = bx << 7;
    const int wm = (w >> 1) << 6, wn = (w & 1) << 6;
    const int kq = l >> 4, lm = l & 15;

    const int zz = bz / d.SK, s = bz - zz * d.SK;
    const int h = d.ahx ? bx : (zz & d.hmask);
    const int g = d.ahx ? zz : (zz >> d.hshift);
    const _Float16* A = d.A + (long)h * d.sAh + (long)g * d.sAg;
    const _Float16* B = d.B + (long)h * d.sBh + (long)g * d.sBg;
    const long Coff = (long)s * d.sSplit + (long)h * d.sCh + (long)g * d.sCg;
    const int kper = d.K / d.SK, kbeg = s * kper;
    const int NT = kper >> 5;

    // staging: each instr = 16 rows x 64 B, 4 lanes per full line.
    const int rS = (w << 4) + (l >> 2);
    const int cS = (l & 3) ^ ((l >> 3) & 3);      // slot ^ ((rS>>1)&3)
    const _Float16* gA0 = A + (long)(m0 + rS) * d.lda + kbeg + cS * 8;
    const _Float16* gB0 = B + (long)(n0 + rS) * d.ldb + kbeg + cS * 8;
    const int lo = w * 1024 + l * 16;

    auto stage = [&](int t) {
        char* dst = sb + (t % 3) * 24576;
        GLD16(gA0 + t * 32,                     dst + lo);           // A rows 0-127
        GLD16(gA0 + (long)128 * d.lda + t * 32, dst + 8192 + lo);    // A rows 128-255
        GLD16(gB0 + t * 32,                     dst + 16384 + lo);   // B rows 0-127
    };

    f32x4 acc[4][4] = {};
    stage(0);
    if (NT > 1) stage(1);
    if (NT > 1) __builtin_amdgcn_s_waitcnt(WAIT_VM3);
    else        __builtin_amdgcn_s_waitcnt(WAIT_VM0);
    __builtin_amdgcn_s_barrier();

    const int sw16 = ((kq ^ ((lm >> 1) & 3)) << 4);   // swizzled 16-B slot
    for (int t = 0; t < NT; ++t) {
        const char* cb = sb + (t % 3) * 24576;
        half8 af[4], bfr[4];
        const char* pa = cb + (wm + lm) * 64 + sw16;
        const char* pb = cb + 16384 + (wn + lm) * 64 + sw16;
        #pragma unroll
        for (int i = 0; i < 4; ++i) {
            af[i]  = *(const half8*)(pa + i * 1024);
            bfr[i] = *(const half8*)(pb + i * 1024);
        }
        #pragma unroll
        for (int mi = 0; mi < 4; ++mi)
            #pragma unroll
            for (int ni = 0; ni < 4; ++ni)
                acc[mi][ni] = __builtin_amdgcn_mfma_f32_16x16x32_f16(af[mi], bfr[ni], acc[mi][ni], 0, 0, 0);
        __builtin_amdgcn_s_waitcnt(WAIT_LGKM0);       // our ds_reads retired
        if (t + 2 < NT) { stage(t + 2); __builtin_amdgcn_s_waitcnt(WAIT_VM3); }
        else if (t + 1 < NT) __builtin_amdgcn_s_waitcnt(WAIT_VM0);
        __builtin_amdgcn_s_barrier();                 // tile t+1 landed+visible
    }

    // C/D layout: col = lane&15, row = (lane>>4)*4 + reg
    if (d.normMode == 0) {
        const int rbase = m0 + wm + kq * 4;
        #pragma unroll
        for (int mi = 0; mi < 4; ++mi) {
            #pragma unroll
            for (int ni = 0; ni < 4; ++ni) {
                const int col = n0 + wn + ni * 16 + lm;
                float cs = d.alpha;
                if (d.csMode == 1 || (d.csMode == 2 && g == 0)) cs *= d.colScale[col];
                #pragma unroll
                for (int r = 0; r < 4; ++r) {
                    const long row = rbase + mi * 16 + r;
                    const float v = acc[mi][ni][r] * cs;
                    const long off = Coff + row * d.ldc + col;
                    if (d.outHalf) ((_Float16*)d.C)[off] = (_Float16)v;
                    else           ((float*)d.C)[off] = v;
                }
            }
        }
        return;
    }

    // ---- fused L2-norm epilogue (block cols = exactly one 128-dim head) ----
    float* part = (float*)sb;                 // part[2][256]
    float ssq[4][4];
    #pragma unroll
    for (int mi = 0; mi < 4; ++mi)
        #pragma unroll
        for (int r = 0; r < 4; ++r) {
            float sq = 0.f;
            #pragma unroll
            for (int ni = 0; ni < 4; ++ni) { const float v = acc[mi][ni][r]; sq += v * v; }
            sq += __shfl_xor(sq, 1, 64);
            sq += __shfl_xor(sq, 2, 64);
            sq += __shfl_xor(sq, 4, 64);
            sq += __shfl_xor(sq, 8, 64);
            ssq[mi][r] = sq;
        }
    if (lm == 0) {
        #pragma unroll
        for (int mi = 0; mi < 4; ++mi)
            #pragma unroll
            for (int r = 0; r < 4; ++r)
                part[(w & 1) * 256 + wm + kq * 4 + mi * 16 + r] = ssq[mi][r];
    }
    __syncthreads();

    #pragma unroll
    for (int mi = 0; mi < 4; ++mi) {
        #pragma unroll
        for (int r = 0; r < 4; ++r) {
            const int rl = wm + kq * 4 + mi * 16 + r;
            const float inv = rsqrtf(part[rl] + part[256 + rl]);
            const long rg = m0 + rl;
            if (d.normMode == 1) {
                #pragma unroll
                for (int ni = 0; ni < 4; ++ni) {
                    const int col = n0 + wn + ni * 16 + lm;
                    ((_Float16*)d.C)[(long)g * 524288 + rg * 1024 + col] =
                        (_Float16)(acc[mi][ni][r] * inv);
                }
            } else if (n0 < 1024) {           // K half -> kn
                #pragma unroll
                for (int ni = 0; ni < 4; ++ni) {
                    const int col = n0 + wn + ni * 16 + lm;
                    ((_Float16*)d.C)[(long)g * 2097152 + rg * 1024 + col] =
                        (_Float16)(acc[mi][ni][r] * inv);
                }
            } else {                          // V half -> vn + xcat right half
                #pragma unroll
                for (int ni = 0; ni < 4; ++ni) {
                    const int nL = n0 - 1024 + wn + ni * 16 + lm;
                    d.vnp[(long)g * 2097152 + rg * 1024 + nL] =
                        (_Float16)(acc[mi][ni][r] * inv);
                    if (rg < 512)
                        d.xop[((long)g * 512 + rg) * 2048 + 1024 + nL] =
                            (_Float16)acc[mi][ni][r];
                }
            }
        }
    }
    // vT raw transposed store (V half)
    if (d.normMode == 2 && n0 >= 1024) {
        #pragma unroll
        for (int mi = 0; mi < 4; ++mi)
            #pragma unroll
            for (int ni = 0; ni < 4; ++ni) {
                const int nL = n0 - 1024 + wn + ni * 16 + lm;
                half4v t;
                t.x = (_Float16)acc[mi][ni][0]; t.y = (_Float16)acc[mi][ni][1];
                t.z = (_Float16)acc[mi][ni][2]; t.w = (_Float16)acc[mi][ni][3];
                *(half4v*)(d.vtp + (long)g * 2097152 + (long)nL * 2048
                           + m0 + wm + kq * 4 + mi * 16) = t;
            }
    }
}

static GD mkgd(const _Float16* A, const _Float16* B, void* C, const float* cscale,
               long sAh, long sAg, long sBh, long sBg, long sSplit, long sCh, long sCg,
               int lda, int ldb, int ldc, int K, int SK, int hmask, int hshift,
               int ahx, int outHalf, int csMode, int nx, int ny, float alpha)
{
    GD d; d.A=A; d.B=B; d.C=C; d.colScale=cscale;
    d.vnp=nullptr; d.vtp=nullptr; d.xop=nullptr;
    d.sAh=sAh; d.sAg=sAg; d.sBh=sBh; d.sBg=sBg; d.sSplit=sSplit; d.sCh=sCh; d.sCg=sCg;
    d.lda=lda; d.ldb=ldb; d.ldc=ldc; d.K=K; d.SK=SK; d.hmask=hmask; d.hshift=hshift;
    d.ahx=ahx; d.outHalf=outHalf; d.csMode=csMode; d.nx=nx; d.ny=ny; d.normMode=0;
    d.alpha=alpha;
    return d;
}

// ---------------------------------------------------------------------------
// prep_all: grid (64,64,7). z<6: weight transposes (f32 -> f16 T);
// z==6: fp32->fp16 cast of x_cls|x_reg (lin = by*64+bx picks slice).
// ---------------------------------------------------------------------------
__global__ __launch_bounds__(256)
void prep_all(const float* __restrict__ x_cls, const float* __restrict__ x_reg,
              const float* __restrict__ Wq_c, const float* __restrict__ Wq_r,
              const float* __restrict__ Wkv_c, const float* __restrict__ Wkv_r,
              const float* __restrict__ Wl_c, const float* __restrict__ Wl_r,
              _Float16* __restrict__ xbf,
              _Float16* __restrict__ WqT, _Float16* __restrict__ WkvT,
              _Float16* __restrict__ WlinT)
{
    const int z = blockIdx.z;
    if (z == 6) {
        const int lin = blockIdx.y * 64 + blockIdx.x;    // [0,4096)
        const int which = lin >> 11;
        const int i = (lin & 2047) * 256 + threadIdx.x;  // float4 index
        const float* s = which ? x_reg : x_cls;
        const float4 v = ((const float4*)s)[i];
        half4v o;
        o.x = (_Float16)v.x; o.y = (_Float16)v.y; o.z = (_Float16)v.z; o.w = (_Float16)v.w;
        ((half4v*)(xbf + (size_t)which * 2097152))[i] = o;
        return;
    }
    __shared__ float t[32][33];
    const float* src; _Float16* dst; int ldsrc, lddst, nx, ky;
    switch (z) {
        case 0: src=Wq_c;  dst=WqT;            ldsrc=1024; lddst=1024; nx=32; ky=32; break;
        case 1: src=Wq_r;  dst=WqT+1048576;    ldsrc=1024; lddst=1024; nx=32; ky=32; break;
        case 2: src=Wkv_c; dst=WkvT;           ldsrc=2048; lddst=1024; nx=64; ky=32; break;
        case 3: src=Wkv_r; dst=WkvT+2097152;   ldsrc=2048; lddst=1024; nx=64; ky=32; break;
        case 4: src=Wl_c;  dst=WlinT;          ldsrc=2048; lddst=2048; nx=64; ky=64; break;
        default:src=Wl_r;  dst=WlinT+4194304;  ldsrc=2048; lddst=2048; nx=64; ky=64; break;
    }
    if ((int)blockIdx.x >= nx || (int)blockIdx.y >= ky) return;
    const int n0 = blockIdx.x << 5, k0 = blockIdx.y << 5;
    const int tx = threadIdx.x & 31, ty = threadIdx.x >> 5;
    #pragma unroll
    for (int j = ty; j < 32; j += 8)
        t[j][tx] = src[(size_t)(k0 + j) * ldsrc + n0 + tx];
    __syncthreads();
    #pragma unroll
    for (int j = ty; j < 32; j += 8)
        dst[(size_t)(n0 + j) * lddst + k0 + tx] = (_Float16)t[tx][j];
}

// ---------------------------------------------------------------------------
// Paired block reduce (256 threads, 4 waves). OP: 0 sum, 1 max.
// ---------------------------------------------------------------------------
template<int OP>
__device__ __forceinline__ void bred2(float& a, float& b, float* lds)
{
    #pragma unroll
    for (int o = 32; o > 0; o >>= 1) {
        const float ua = __shfl_xor(a, o, 64);
        const float ub = __shfl_xor(b, o, 64);
        a = OP ? fmaxf(a, ua) : a + ua;
        b = OP ? fmaxf(b, ub) : b + ub;
    }
    __syncthreads();
    if ((threadIdx.x & 63) == 0) {
        const int wi = threadIdx.x >> 6;
        lds[wi] = a; lds[4 + wi] = b;
    }
    __syncthreads();
    a = OP ? fmaxf(fmaxf(lds[0], lds[1]), fmaxf(lds[2], lds[3]))
           : lds[0] + lds[1] + lds[2] + lds[3];
    b = OP ? fmaxf(fmaxf(lds[4], lds[5]), fmaxf(lds[6], lds[7]))
           : lds[4] + lds[5] + lds[6] + lds[7];
}

// ---------------------------------------------------------------------------
// sb2 (vectorized; NO max-subtraction — kept from r10, the good half):
// scores are bounded (|cos|<=1 -> |S| <= 25.1, exp <= 8e10 << f32 max;
// head-mean <= 1 -> exp <= e), so exp(x)/sum exp(x) is safe in f32 and
// mathematically identical to the max-subtracted softmax. 18 barriers vs 38.
// Thread t owns 8 contiguous cols. S16 [16][512][2048] fp16 (0-7 cls,
// 8-15 reg); simPart [2s][2g][512][2048] f32 (2-way split-K summed here).
// ---------------------------------------------------------------------------
__global__ __launch_bounds__(256)
void sb2_kernel(const _Float16* __restrict__ S16, const float* __restrict__ simPart,
                _Float16* __restrict__ attn,
                _Float16* __restrict__ wc, _Float16* __restrict__ wr)
{
    __shared__ float lds[8];
    const int q = blockIdx.x, t = threadIdx.x;
    const int c0 = t * 8;
    float asum[8] = {};
    for (int hh = 0; hh < 8; ++hh) {
        const size_t rb = (size_t)(hh * 512 + q) * 2048 + c0;
        const half8 hc = *(const half8*)(S16 + rb);
        const half8 hr = *(const half8*)(S16 + 8388608 + rb);
        float vc[8], vr[8];
        float sc = 0.f, sr = 0.f;
        #pragma unroll
        for (int j = 0; j < 8; ++j) {
            vc[j] = expf((float)hc[j]); sc += vc[j];
            vr[j] = expf((float)hr[j]); sr += vr[j];
        }
        bred2<0>(sc, sr, lds);
        const float ic = 0.5f / sc, ir = 0.5f / sr;
        half8 oa;
        #pragma unroll
        for (int j = 0; j < 8; ++j) {
            const float a = vc[j] * ic + vr[j] * ir;
            oa[j] = (_Float16)a;
            asum[j] += a;
        }
        *(half8*)(attn + rb) = oa;
    }
    const size_t qb = (size_t)q * 2048 + c0;
    float sim[8], reg[8];
    {
        const float4 a0 = *(const float4*)(simPart + qb);
        const float4 a1 = *(const float4*)(simPart + qb + 4);
        const float4 b0 = *(const float4*)(simPart + 2097152 + qb);
        const float4 b1 = *(const float4*)(simPart + 2097152 + qb + 4);
        sim[0]=a0.x+b0.x; sim[1]=a0.y+b0.y; sim[2]=a0.z+b0.z; sim[3]=a0.w+b0.w;
        sim[4]=a1.x+b1.x; sim[5]=a1.y+b1.y; sim[6]=a1.z+b1.z; sim[7]=a1.w+b1.w;
        const float4 c0_ = *(const float4*)(simPart + 1048576 + qb);
        const float4 c1_ = *(const float4*)(simPart + 1048576 + qb + 4);
        const float4 d0_ = *(const float4*)(simPart + 2097152 + 1048576 + qb);
        const float4 d1_ = *(const float4*)(simPart + 2097152 + 1048576 + qb + 4);
        reg[0]=c0_.x+d0_.x; reg[1]=c0_.y+d0_.y; reg[2]=c0_.z+d0_.z; reg[3]=c0_.w+d0_.w;
        reg[4]=c1_.x+d1_.x; reg[5]=c1_.y+d1_.y; reg[6]=c1_.z+d1_.z; reg[7]=c1_.w+d1_.w;
    }
    float em[8], emo[8];
    float s1 = 0.f, s2 = 0.f;
    #pragma unroll
    for (int j = 0; j < 8; ++j) {
        const float e = expf(asum[j] * 0.125f);       // bounded by e^1
        const float m  = sim[j] > 0.75f ? 1.f : 0.f;
        const float mo = reg[j] > 0.99f ? 1.f : 0.f;
        em[j] = e * m; emo[j] = e * m * mo;
        s1 += em[j]; s2 += emo[j];
    }
    bred2<0>(s1, s2, lds);
    const float i1 = 1.f / s1, i2 = 1.f / s2;
    half8 o1, o2;
    #pragma unroll
    for (int j = 0; j < 8; ++j) {
        o1[j] = (_Float16)(em[j] * i1);
        o2[j] = (_Float16)(emo[j] * i2);
    }
    *(half8*)(wc + qb) = o1;
    *(half8*)(wr + qb) = o2;
}

// ---------------------------------------------------------------------------
// build_xcat (left half only; right half written by M1 epilogue):
// xcat[g][n][j<1024] = 4-way reduce of fp16 attn@V partials. Grid 512 x 256,
// half8-vectorized.
// ---------------------------------------------------------------------------
__global__ __launch_bounds__(256)
void build_xcat(const _Float16* __restrict__ xcatPart, _Float16* __restrict__ xcat)
{
    const int v8 = blockIdx.x * 256 + threadIdx.x;    // [0, 131072)
    const int g = v8 >> 16;
    const int n = (v8 >> 7) & 511;
    const int j = (v8 & 127) * 8;
    const size_t p = (size_t)g * 524288 + (size_t)n * 1024 + j;
    float a[8] = {};
    #pragma unroll
    for (int s = 0; s < 4; ++s) {
        const half8 v = *(const half8*)(xcatPart + (size_t)s * 1048576 + p);
        #pragma unroll
        for (int k = 0; k < 8; ++k) a[k] += (float)v[k];
    }
    half8 o;
    #pragma unroll
    for (int k = 0; k < 8; ++k) o[k] = (_Float16)a[k];
    *(half8*)(xcat + ((size_t)g * 512 + n) * 2048 + j) = o;
}

// ---------------------------------------------------------------------------
// finalize d_out [2][512][3072] (vectorized float4): cols<1024 4-way avePart
// reduce; cols>=1024 4-way outPart reduce + bias. Grid 3072 x 256.
// ---------------------------------------------------------------------------
__global__ __launch_bounds__(256)
void finalize(const float* __restrict__ avePart, const float* __restrict__ outPart,
              const float* __restrict__ b_lin, const float* __restrict__ b_lin_reg,
              float* __restrict__ out)
{
    const int v4 = blockIdx.x * 256 + threadIdx.x;    // [0, 786432)
    const size_t base = (size_t)v4 * 4;
    const int c = (int)(base % 3072);
    const int r = (int)((base / 3072) & 511);
    const int g = (int)(base / (3072 * 512));
    float4 v;
    if (c < 1024) {
        const size_t p = (size_t)g * 524288 + (size_t)r * 1024 + c;
        v = make_float4(0.f, 0.f, 0.f, 0.f);
        #pragma unroll
        for (int s = 0; s < 4; ++s) {
            const float4 u = *(const float4*)(avePart + (size_t)s * 1048576 + p);
            v.x += u.x; v.y += u.y; v.z += u.z; v.w += u.w;
        }
    } else {
        const int cc = c - 1024;
        v = *(const float4*)((g ? b_lin_reg : b_lin) + cc);
        const size_t p = (size_t)g * 1048576 + (size_t)r * 2048 + cc;
        #pragma unroll
        for (int s = 0; s < 4; ++s) {
            const float4 u = *(const float4*)(outPart + (size_t)s * 2097152 + p);
            v.x += u.x; v.y += u.y; v.z += u.z; v.w += u.w;
        }
    }
    *(float4*)(out + base) = v;
}

extern "C" void kernel_launch(void* const* d_in, const int* in_sizes, int n_in,
                              void* d_out, int out_size, void* d_ws, size_t ws_size,
                              hipStream_t stream)
{
    const float* x_cls     = (const float*)d_in[0];
    const float* x_reg     = (const float*)d_in[1];
    const float* cls_score = (const float*)d_in[2];
    const float* W_q_cls   = (const float*)d_in[4];
    const float* W_kv_cls  = (const float*)d_in[5];
    const float* W_q_reg   = (const float*)d_in[6];
    const float* W_kv_reg  = (const float*)d_in[7];
    const float* W_lin     = (const float*)d_in[8];
    const float* b_lin     = (const float*)d_in[9];
    const float* W_lin_reg = (const float*)d_in[10];
    const float* b_lin_reg = (const float*)d_in[11];
    float* out = (float*)d_out;

    if (ws_size < (size_t)124 * 1048576) return;

    // Workspace overlay (MiB offsets), peak 106 MiB. Lifetimes:
    //  [0,16)   WlinT    prep -> M8
    //  [16,24)  vT       M1 -> M3
    //  [24,26)  w_c      sb2 -> M3        [26,28) w_r
    //  [28,30)  qn       M1 -> M2(sc)   } attn_h [28,44) overlays after M2
    //  [30,38)  kn       M1 -> M2(sc)   }
    //  [38,46)  vn       M1 -> M2(vs)   }
    //  [46,54)  xbf      prep -> M1     } simPart [46,62) overlays after M1;
    //  [54,62)  WkvT     prep -> M1     }  avePart [46,62) overlays after sb2
    //  [62,66)  WqT      prep -> M1     } xcatPart [62,70) overlays after sb2
    //  [66,98)  S16      M2(sc) -> sb2  }  (S16 dead after sb2)
    //  [70,102) outPart  M8 -> finalize    (over dead S16 + fresh [98,102))
    //  [102,106) xcat16  M1(right)+build_xcat(left) -> M8
    char* W = (char*)d_ws;
    auto at = [&](size_t mb) { return (void*)(W + mb * 1048576); };
    _Float16* WlinT   = (_Float16*)at(0);
    _Float16* vT      = (_Float16*)at(16);
    _Float16* w_c     = (_Float16*)at(24);
    _Float16* w_r     = (_Float16*)at(26);
    _Float16* qn      = (_Float16*)at(28);
    _Float16* kn      = (_Float16*)at(30);
    _Float16* vn      = (_Float16*)at(38);
    _Float16* xbf     = (_Float16*)at(46);
    _Float16* WkvT    = (_Float16*)at(54);
    _Float16* WqT     = (_Float16*)at(62);
    _Float16* S16     = (_Float16*)at(66);
    float*    simPart = (float*)at(46);      // [2s][2g][512][2048] f32, 16 MB
    _Float16* attn_h  = (_Float16*)at(28);   // [16][512][2048] fp16, 16 MB
    float*    avePart = (float*)at(46);      // [4s][2g][512][1024] f32, 16 MB
    _Float16* xcatPart= (_Float16*)at(62);   // [4s][2g][512][1024] fp16, 8 MB
    float*    outPart = (float*)at(70);      // [4s][2g][512][2048] f32, 32 MB
    _Float16* xcat16  = (_Float16*)at(102);  // [2][512][2048] fp16, 4 MB

    // Phase 1: prep (cast + all transposes, one launch)
    prep_all<<<dim3(64, 64, 7), 256, 0, stream>>>(
        x_cls, x_reg, W_q_cls, W_q_reg, W_kv_cls, W_kv_reg, W_lin, W_lin_reg,
        xbf, WqT, WkvT, WlinT);

    // Phase 2 (M1): q-proj + kv-proj with fused L2-norm epilogues; kv also
    // writes raw V (rows<512) straight into xcat16's right half.
    {
        GD q  = mkgd(xbf, WqT, qn, nullptr,
                     0, 2097152, 0, 1048576, 0, 0, 0,
                     1024, 1024, 1024, 1024, 1, 0, 0, 1, 0, 0, 8, 2, 1.f);
        q.normMode = 1;
        GD kv = mkgd(xbf, WkvT, kn, nullptr,
                     0, 2097152, 0, 2097152, 0, 0, 0,
                     1024, 1024, 1024, 1024, 1, 0, 0, 1, 0, 0, 16, 8, 1.f);
        kv.normMode = 2; kv.vnp = vn; kv.vtp = vT; kv.xop = xcat16;
        hgemm3<<<dim3(16, 8, 4), 512, 0, stream>>>(q, kv, 2);
    }

    // Phase 3 (M2): v-sim (SK=2, f32 partials -> summed in sb2) + scores
    {
        GD vs = mkgd(vn, vn, simPart, nullptr,
                     0, 2097152, 0, 2097152, 2097152, 0, 1048576,
                     1024, 1024, 2048, 1024, 2, 0, 0, 0, 0, 0, 16, 2, 0.125f);
        GD sc = mkgd(qn, kn, S16, cls_score,
                     128, 524288, 128, 2097152, 0, 1048576, 8388608,
                     1024, 1024, 2048, 128, 1, 7, 3, 0, 1, 2, 16, 2, 25.f);
        hgemm3<<<dim3(16, 2, 20), 512, 0, stream>>>(vs, sc, 4);
    }

    // Phase 4: fused dual softmax + blend + head-mean + round2 weights
    sb2_kernel<<<512, 256, 0, stream>>>(S16, simPart, attn_h, w_c, w_r);

    // Phase 5 (M3): attn@V (AHX, SK=4, fp16 partials) + ave (SK=4, f32)
    {
        GD av = mkgd(attn_h, vT, xcatPart, nullptr,
                     1048576, 0, 0, 2097152, 1048576, 0, 524288,
                     2048, 2048, 1024, 2048, 4, 0, 0, 1, 1, 0, 8, 2, 1.f);
        GD ae = mkgd(w_c, vT, avePart, nullptr,
                     0, 1048576, 0, 2097152, 1048576, 0, 524288,
                     2048, 2048, 1024, 2048, 4, 0, 0, 0, 0, 0, 8, 2, 1.f);
        hgemm3<<<dim3(8, 2, 16), 512, 0, stream>>>(av, ae, 8);
    }

    // Phase 6: xcat left-half assembly (4-way fp16 reduce), half8-vectorized
    build_xcat<<<512, 256, 0, stream>>>(xcatPart, xcat16);

    // Phase 7 (M8): out-linears (SK=4, fp32 partials)
    {
        GD ol = mkgd(xcat16, WlinT, outPart, nullptr,
                     0, 1048576, 0, 4194304, 2097152, 0, 1048576,
                     2048, 2048, 2048, 2048, 4, 0, 0, 0, 0, 0, 16, 2, 1.f);
        hgemm3<<<dim3(16, 2, 8), 512, 0, stream>>>(ol, ol, 8);
    }

    // Phase 8: write d_out, float4-vectorized
    finalize<<<3072, 256, 0, stream>>>(avePart, outPart, b_lin, b_lin_reg, out);
}